// Round 16
// baseline (49.407 us; speedup 1.0000x reference)
//
#include <hip/hip_runtime.h>

#define NST 10
#define NLBL 50
#define BATCH 256
#define TLEN 1024
#define TPB 256
#define HALO 8
#define ROWS (TPB + 2*HALO)   // 272
#define EPAD 13
#define PRPAD 12
#define SC 1.0e15f
#define LN2F 0.69314718055994531f

static __device__ __forceinline__ float dppswap(float x) {
    // quad_perm [1,0,3,2]: lane 2k <-> 2k+1. Pure VALU, no LDS.
    return __int_as_float(__builtin_amdgcn_mov_dpp(__float_as_int(x), 0xB1, 0xF, 0xF, true));
}

__global__ __launch_bounds__(256, 4)
void k_all(const int* __restrict__ sent,
           const float* __restrict__ W,
           const float* __restrict__ trans,
           const float* __restrict__ outw,
           float* __restrict__ out) {
    __shared__ alignas(16) float Elds[ROWS][EPAD];   // 14144 B
    __shared__ alignas(16) float prl[TPB][PRPAD];    // 12288 B
    __shared__ float Tl[100];
    __shared__ float Ttl[100];
    __shared__ float Ol[NST][NLBL];                  // 2000 B
    __shared__ float wscr[4][16];                    // per-wave Ol row inverses

    const int tid = threadIdx.x;
    const int b   = (int)blockIdx.x >> 2;
    const int tb  = ((int)blockIdx.x & 3) * TPB;

    // ---- parallel, max-free param prep (params bounded in [-0.5,0.5]) ----
    if (tid < 250) {
        float* of = &Ol[0][0];
        const int i = 2 * tid;
        of[i]     = __expf(outw[i]);
        of[i + 1] = __expf(outw[i + 1]);
    }
    if (tid < NST) {
        float e[10]; float s = 0.f;
        #pragma unroll
        for (int j = 0; j < 10; ++j) { e[j] = __expf(trans[tid*10 + j]); s += e[j]; }
        float inv = 1.f / s;
        #pragma unroll
        for (int j = 0; j < 10; ++j) { Tl[tid*10 + j] = e[j]*inv; Ttl[j*10 + tid] = e[j]*inv; }
    }

    // ---- emission staging: gather W[tok], softmax (max-free), -> LDS ----
    const int* sb = sent + b*TLEN;
    for (int r = tid; r < ROWS; r += 256) {
        int p  = tb - HALO + r;
        int pc = min(max(p, 0), TLEN-1);
        int tok = sb[pc];
        const float2* w2 = reinterpret_cast<const float2*>(W + (size_t)tok*NST);
        float2 q0=w2[0], q1=w2[1], q2=w2[2], q3=w2[3], q4=w2[4];
        float e[10] = {q0.x,q0.y,q1.x,q1.y,q2.x,q2.y,q3.x,q3.y,q4.x,q4.y};
        float s = 0.f;
        #pragma unroll
        for (int j=0;j<10;++j) { e[j] = __expf(e[j]); s += e[j]; }
        float inv = 1.f/s;
        #pragma unroll
        for (int j=0;j<10;++j) Elds[r][j] = e[j]*inv;
    }
    __syncthreads();   // barrier 1 (the ONLY barrier): Elds + exp(Ol) + T tables visible

    // ---- pair decomposition: lanes (2k,2k+1) share one 2-step chunk ----
    const int q   = tid & 1;          // 0: states 0..4, 1: states 5..9
    const int pr_ = tid >> 1;         // pair index 0..127
    const int j0  = 5*q;
    const int j1  = 5 - j0;           // partner's state base
    const int t0  = tb + 2*pr_;       // chunk = {t0, t0+1}
    const int lr0 = 2*pr_;            // LDS row of position t0-HALO
    const int lre = lr0 + 2*HALO + 1; // LDS row of position t0+HALO+1

    float as0[5], as1[5];
    {
        // ---- forward: 9 steps from t0-HALO; keep alpha(t0), alpha(t0+1) ----
        float Ta[5][5], Tb[5][5];
        #pragma unroll
        for (int r=0;r<5;++r)
            #pragma unroll
            for (int k=0;k<5;++k) {
                Ta[r][k] = Tl[(j0+r)*10 + j0 + k];
                Tb[r][k] = Tl[(j0+r)*10 + j1 + k];
            }

        float m_[5];
        #pragma unroll
        for (int k=0;k<5;++k) m_[k] = Elds[lr0][j0+k] * SC;

        #pragma unroll
        for (int i=1;i<=HALO+1;++i) {
            const int p = t0 - HALO + i;
            float pp[5];
            #pragma unroll
            for (int k=0;k<5;++k) pp[k] = dppswap(m_[k]);
            float an[5];
            #pragma unroll
            for (int r=0;r<5;++r) {
                float accA = 0.f, accB = 0.f;
                #pragma unroll
                for (int k=0;k<5;++k) accA = fmaf(Ta[r][k], m_[k], accA);
                #pragma unroll
                for (int k=0;k<5;++k) accB = fmaf(Tb[r][k], pp[k], accB);
                an[r] = (accA + accB) * Elds[lr0+i][j0+r];
            }
            const bool upd = (p >= 1);
            #pragma unroll
            for (int r=0;r<5;++r) m_[r] = upd ? an[r] : m_[r];
            if (i == HALO) {
                #pragma unroll
                for (int r=0;r<5;++r) as0[r] = m_[r];
            }
        }
        #pragma unroll
        for (int r=0;r<5;++r) as1[r] = m_[r];
    }

    {
        // ---- backward: 9 steps from t0+HALO+1 down to t0; posterior -> prl ----
        float Ta[5][5], Tb[5][5];
        #pragma unroll
        for (int r=0;r<5;++r)
            #pragma unroll
            for (int k=0;k<5;++k) {
                Ta[r][k] = Ttl[(j0+r)*10 + j0 + k];
                Tb[r][k] = Ttl[(j0+r)*10 + j1 + k];
            }

        const int pe = t0 + HALO + 1;
        float g_[5];
        #pragma unroll
        for (int k=0;k<5;++k) g_[k] = Elds[lre][j0+k] * SC;

        #pragma unroll
        for (int i=1;i<=HALO+1;++i) {
            const int p = pe - i;
            float pp[5];
            #pragma unroll
            for (int k=0;k<5;++k) pp[k] = dppswap(g_[k]);
            float u[5];
            #pragma unroll
            for (int r=0;r<5;++r) {
                float accA = 0.f, accB = 0.f;
                #pragma unroll
                for (int k=0;k<5;++k) accA = fmaf(Ta[r][k], g_[k], accA);
                #pragma unroll
                for (int k=0;k<5;++k) accB = fmaf(Tb[r][k], pp[k], accB);
                u[r] = accA + accB;
            }
            const bool last = (p == TLEN-1);
            #pragma unroll
            for (int r=0;r<5;++r) u[r] = last ? SC : u[r];
            if (i == HALO) {          // p == t0+1
                float pv[5]; float sum = 0.f;
                #pragma unroll
                for (int r=0;r<5;++r) { pv[r] = as1[r]*u[r]; sum += pv[r]; }
                float full = sum + dppswap(sum);
                #pragma unroll
                for (int r=0;r<5;++r) prl[2*pr_+1][j0+r] = pv[r];
                prl[2*pr_+1][10] = __log2f(full);
            }
            if (i == HALO+1) {        // p == t0
                float pv[5]; float sum = 0.f;
                #pragma unroll
                for (int r=0;r<5;++r) { pv[r] = as0[r]*u[r]; sum += pv[r]; }
                float full = sum + dppswap(sum);
                #pragma unroll
                for (int r=0;r<5;++r) prl[2*pr_][j0+r] = pv[r];
                prl[2*pr_][10] = __log2f(full);
            }
            const bool keep = (p > TLEN-1);
            #pragma unroll
            for (int r=0;r<5;++r) {
                float gn = Elds[lre - i][j0+r] * u[r];
                g_[r] = keep ? g_[r] : gn;
            }
        }
    }
    // NO barrier: prl rows [64w,64w+64) are written by wave w's own lanes and read
    // only by wave w's combine below. Ol normalization is done per-wave. Elds is
    // not reused. Waves proceed independently from here -> stalls decorrelate.

    // ---- combine: wave-local, barrier-free, direct stores ----
    const int wid  = tid >> 6;
    const int lane = tid & 63;
    const int lg = lane & 7;              // label group
    const int rv = lane >> 3;             // 0..7
    const int lb = lg * 7;                // labels lb..lb+6 (masked at 50)

    // per-wave Ol row inverses via wave-private LDS scratch (intra-wave ordering only)
    if (lane < NST) {
        float s = 0.f;
        #pragma unroll 10
        for (int l = 0; l < NLBL; ++l) s += Ol[lane][l];
        wscr[wid][lane] = 1.f / s;
    }
    float winv[10];
    #pragma unroll
    for (int s = 0; s < 10; ++s) winv[s] = wscr[wid][s];

    float vO[10][7];
    #pragma unroll
    for (int s=0;s<10;++s)
        #pragma unroll
        for (int k=0;k<7;++k) vO[s][k] = (lb + k < NLBL) ? Ol[s][lb+k] * winv[s] : 0.f;

    float* obW = out + ((size_t)b*TLEN + tb + wid*64)*NLBL;
    #pragma unroll 2
    for (int pass = 0; pass < 8; ++pass) {
        const int rloc = rv + 8*pass;         // row within wave's 64-row span
        const int t = wid*64 + rloc;          // block row (written by this wave)
        const float4* pr4 = reinterpret_cast<const float4*>(&prl[t][0]);
        const float4 pA = pr4[0];
        const float4 pB = pr4[1];
        const float4 pC = pr4[2];             // [8],[9],[10]=ls,[11] unused
        float pv[10] = {pA.x,pA.y,pA.z,pA.w,pB.x,pB.y,pB.z,pB.w,pC.x,pC.y};
        const float ls = pC.z;
        float* orow = obW + rloc*NLBL + lb;
        #pragma unroll
        for (int k=0;k<7;++k) {
            float d = 0.f;
            #pragma unroll
            for (int s=0;s<10;++s) d = fmaf(pv[s], vO[s][k], d);
            float v = (__log2f(d) - ls) * LN2F;
            if (lb + k < NLBL) orow[k] = v;
        }
    }
}

extern "C" void kernel_launch(void* const* d_in, const int* in_sizes, int n_in,
                              void* d_out, int out_size, void* d_ws, size_t ws_size,
                              hipStream_t stream) {
    const int*   sent  = (const int*)d_in[0];
    const float* W     = (const float*)d_in[1];
    const float* trans = (const float*)d_in[2];
    const float* outw  = (const float*)d_in[3];
    float* out = (float*)d_out;

    hipLaunchKernelGGL(k_all, dim3(BATCH * (TLEN / TPB)), dim3(256), 0, stream,
                       sent, W, trans, outw, out);
}

// Round 17
// 48.845 us; speedup vs baseline: 1.0115x; 1.0115x over previous
//
#include <hip/hip_runtime.h>

#define NST 10
#define NLBL 50
#define BATCH 256
#define TLEN 1024
#define TPB 64
#define HALO 8
#define ROWS (TPB + 2*HALO)   // 80
#define EPAD 13
#define PRPAD 12
#define SC 1.0e15f
#define LN2F 0.69314718055994531f

static __device__ __forceinline__ float dppswap(float x) {
    // quad_perm [1,0,3,2]: lane 2k <-> 2k+1. Pure VALU, no LDS.
    return __int_as_float(__builtin_amdgcn_mov_dpp(__float_as_int(x), 0xB1, 0xF, 0xF, true));
}

__global__ __launch_bounds__(64, 4)
void k_all(const int* __restrict__ sent,
           const float* __restrict__ W,
           const float* __restrict__ trans,
           const float* __restrict__ outw,
           float* __restrict__ out) {
    // ~9.9 KB total -> 16 blocks/CU; single wave per block -> NO barriers anywhere.
    __shared__ float Elds[ROWS][EPAD];              // 4160 B
    __shared__ alignas(16) float prl[TPB][PRPAD];   // 3072 B
    __shared__ float Tl[100];
    __shared__ float Ttl[100];
    __shared__ float Ol[NST][NLBL];                 // 2000 B
    __shared__ float osum[16];

    const int lane = threadIdx.x;                   // 0..63
    const int b    = (int)blockIdx.x >> 4;
    const int tb   = ((int)blockIdx.x & 15) * TPB;

    const int* sb = sent + b*TLEN;

    // ---- issue BOTH E-row gathers up front (latency overlapped by param prep) ----
    const int pc0  = min(max(tb - HALO + lane, 0), TLEN-1);
    const int tok0 = sb[pc0];
    const float2* wa = reinterpret_cast<const float2*>(W + (size_t)tok0*NST);
    const float2 a0=wa[0], a1=wa[1], a2=wa[2], a3=wa[3], a4=wa[4];

    const bool has2 = (lane < ROWS - TPB);          // lanes 0..15
    const int pc1  = min(max(tb - HALO + TPB + lane, 0), TLEN-1);
    const int tok1 = sb[has2 ? pc1 : pc0];
    const float2* wb = reinterpret_cast<const float2*>(W + (size_t)tok1*NST);
    float2 b0, b1, b2, b3, b4;
    if (has2) { b0=wb[0]; b1=wb[1]; b2=wb[2]; b3=wb[3]; b4=wb[4]; }

    // ---- param prep (max-free: params bounded in [-0.5,0.5]) ----
    {
        float* of = &Ol[0][0];
        for (int i = lane; i < NST*NLBL; i += 64) of[i] = __expf(outw[i]);
    }
    if (lane < NST) {
        float e[10]; float s = 0.f;
        #pragma unroll
        for (int j = 0; j < 10; ++j) { e[j] = __expf(trans[lane*10 + j]); s += e[j]; }
        float inv = 1.f / s;
        #pragma unroll
        for (int j = 0; j < 10; ++j) { Tl[lane*10 + j] = e[j]*inv; Ttl[j*10 + lane] = e[j]*inv; }
    }

    // ---- emission softmax -> Elds (rows lane and lane+64) ----
    {
        float e[10] = {a0.x,a0.y,a1.x,a1.y,a2.x,a2.y,a3.x,a3.y,a4.x,a4.y};
        float s = 0.f;
        #pragma unroll
        for (int j=0;j<10;++j) { e[j] = __expf(e[j]); s += e[j]; }
        float inv = 1.f/s;
        #pragma unroll
        for (int j=0;j<10;++j) Elds[lane][j] = e[j]*inv;
    }
    if (has2) {
        float e[10] = {b0.x,b0.y,b1.x,b1.y,b2.x,b2.y,b3.x,b3.y,b4.x,b4.y};
        float s = 0.f;
        #pragma unroll
        for (int j=0;j<10;++j) { e[j] = __expf(e[j]); s += e[j]; }
        float inv = 1.f/s;
        #pragma unroll
        for (int j=0;j<10;++j) Elds[lane + TPB][j] = e[j]*inv;
    }

    // ---- Ol row normalization (wave-local; DS ordering suffices, proven R16) ----
    if (lane < NST) {
        float s = 0.f;
        #pragma unroll 10
        for (int l = 0; l < NLBL; ++l) s += Ol[lane][l];
        osum[lane] = 1.f / s;
    }
    #pragma unroll
    for (int row = 0; row < NST; ++row)
        if (lane < NLBL) Ol[row][lane] *= osum[row];

    // ---- pair decomposition: lanes (2k,2k+1) share one 2-step chunk ----
    const int q   = lane & 1;         // 0: states 0..4, 1: states 5..9
    const int pr_ = lane >> 1;        // pair index 0..31
    const int j0  = 5*q;
    const int j1  = 5 - j0;           // partner's state base
    const int t0  = tb + 2*pr_;       // chunk = {t0, t0+1}
    const int lr0 = 2*pr_;            // LDS row of position t0-HALO
    const int lre = lr0 + 2*HALO + 1; // LDS row of position t0+HALO+1

    float as0[5], as1[5];
    {
        // ---- forward: 9 steps from t0-HALO; keep alpha(t0), alpha(t0+1) ----
        float Ta[5][5], Tb[5][5];
        #pragma unroll
        for (int r=0;r<5;++r)
            #pragma unroll
            for (int k=0;k<5;++k) {
                Ta[r][k] = Tl[(j0+r)*10 + j0 + k];
                Tb[r][k] = Tl[(j0+r)*10 + j1 + k];
            }

        float m_[5];
        #pragma unroll
        for (int k=0;k<5;++k) m_[k] = Elds[lr0][j0+k] * SC;

        #pragma unroll
        for (int i=1;i<=HALO+1;++i) {
            const int p = t0 - HALO + i;
            float pp[5];
            #pragma unroll
            for (int k=0;k<5;++k) pp[k] = dppswap(m_[k]);
            float an[5];
            #pragma unroll
            for (int r=0;r<5;++r) {
                float accA = 0.f, accB = 0.f;
                #pragma unroll
                for (int k=0;k<5;++k) accA = fmaf(Ta[r][k], m_[k], accA);
                #pragma unroll
                for (int k=0;k<5;++k) accB = fmaf(Tb[r][k], pp[k], accB);
                an[r] = (accA + accB) * Elds[lr0+i][j0+r];
            }
            const bool upd = (p >= 1);
            #pragma unroll
            for (int r=0;r<5;++r) m_[r] = upd ? an[r] : m_[r];
            if (i == HALO) {
                #pragma unroll
                for (int r=0;r<5;++r) as0[r] = m_[r];
            }
        }
        #pragma unroll
        for (int r=0;r<5;++r) as1[r] = m_[r];
    }

    {
        // ---- backward: 9 steps from t0+HALO+1 down to t0; posterior -> prl ----
        float Ta[5][5], Tb[5][5];
        #pragma unroll
        for (int r=0;r<5;++r)
            #pragma unroll
            for (int k=0;k<5;++k) {
                Ta[r][k] = Ttl[(j0+r)*10 + j0 + k];
                Tb[r][k] = Ttl[(j0+r)*10 + j1 + k];
            }

        const int pe = t0 + HALO + 1;
        float g_[5];
        #pragma unroll
        for (int k=0;k<5;++k) g_[k] = Elds[lre][j0+k] * SC;

        #pragma unroll
        for (int i=1;i<=HALO+1;++i) {
            const int p = pe - i;
            float pp[5];
            #pragma unroll
            for (int k=0;k<5;++k) pp[k] = dppswap(g_[k]);
            float u[5];
            #pragma unroll
            for (int r=0;r<5;++r) {
                float accA = 0.f, accB = 0.f;
                #pragma unroll
                for (int k=0;k<5;++k) accA = fmaf(Ta[r][k], g_[k], accA);
                #pragma unroll
                for (int k=0;k<5;++k) accB = fmaf(Tb[r][k], pp[k], accB);
                u[r] = accA + accB;
            }
            const bool last = (p == TLEN-1);
            #pragma unroll
            for (int r=0;r<5;++r) u[r] = last ? SC : u[r];
            if (i == HALO) {          // p == t0+1
                float pv[5]; float sum = 0.f;
                #pragma unroll
                for (int r=0;r<5;++r) { pv[r] = as1[r]*u[r]; sum += pv[r]; }
                float full = sum + dppswap(sum);
                #pragma unroll
                for (int r=0;r<5;++r) prl[2*pr_+1][j0+r] = pv[r];
                prl[2*pr_+1][10] = __log2f(full);
            }
            if (i == HALO+1) {        // p == t0
                float pv[5]; float sum = 0.f;
                #pragma unroll
                for (int r=0;r<5;++r) { pv[r] = as0[r]*u[r]; sum += pv[r]; }
                float full = sum + dppswap(sum);
                #pragma unroll
                for (int r=0;r<5;++r) prl[2*pr_][j0+r] = pv[r];
                prl[2*pr_][10] = __log2f(full);
            }
            const bool keep = (p > TLEN-1);
            #pragma unroll
            for (int r=0;r<5;++r) {
                float gn = Elds[lre - i][j0+r] * u[r];
                g_[r] = keep ? g_[r] : gn;
            }
        }
    }

    // ---- combine: same wave, no barrier; 8 lanes per row x 7 labels; direct stores ----
    const int lg = lane & 7;              // label group
    const int rv = lane >> 3;             // 0..7
    const int lb = lg * 7;                // labels lb..lb+6 (masked at 50)

    float vO[10][7];
    #pragma unroll
    for (int s=0;s<10;++s)
        #pragma unroll
        for (int k=0;k<7;++k) vO[s][k] = (lb + k < NLBL) ? Ol[s][lb+k] : 0.f;

    float* obW = out + ((size_t)b*TLEN + tb)*NLBL;
    #pragma unroll 2
    for (int pass = 0; pass < 8; ++pass) {
        const int rloc = rv + 8*pass;         // row within this block's 64-row span
        const float4* pr4 = reinterpret_cast<const float4*>(&prl[rloc][0]);
        const float4 pA = pr4[0];
        const float4 pB = pr4[1];
        const float4 pC = pr4[2];             // [8],[9],[10]=ls,[11] unused
        float pv[10] = {pA.x,pA.y,pA.z,pA.w,pB.x,pB.y,pB.z,pB.w,pC.x,pC.y};
        const float ls = pC.z;
        float* orow = obW + rloc*NLBL + lb;
        #pragma unroll
        for (int k=0;k<7;++k) {
            float d = 0.f;
            #pragma unroll
            for (int s=0;s<10;++s) d = fmaf(pv[s], vO[s][k], d);
            float v = (__log2f(d) - ls) * LN2F;
            if (lb + k < NLBL) orow[k] = v;
        }
    }
}

extern "C" void kernel_launch(void* const* d_in, const int* in_sizes, int n_in,
                              void* d_out, int out_size, void* d_ws, size_t ws_size,
                              hipStream_t stream) {
    const int*   sent  = (const int*)d_in[0];
    const float* W     = (const float*)d_in[1];
    const float* trans = (const float*)d_in[2];
    const float* outw  = (const float*)d_in[3];
    float* out = (float*)d_out;

    hipLaunchKernelGGL(k_all, dim3(BATCH * (TLEN / TPB)), dim3(64), 0, stream,
                       sent, W, trans, outw, out);
}

// Round 18
// 48.319 us; speedup vs baseline: 1.0225x; 1.0109x over previous
//
#include <hip/hip_runtime.h>

#define NST 10
#define NLBL 50
#define BATCH 256
#define TLEN 1024
#define TPB 256
#define HALO 8
#define ROWS (TPB + 2*HALO)   // 272
#define EPAD 13
#define PRPAD 12
#define SC 1.0e15f
#define LN2F 0.69314718055994531f

static __device__ __forceinline__ float dppswap(float x) {
    // quad_perm [1,0,3,2]: lane 2k <-> 2k+1. Pure VALU, no LDS.
    return __int_as_float(__builtin_amdgcn_mov_dpp(__float_as_int(x), 0xB1, 0xF, 0xF, true));
}

__global__ __launch_bounds__(256, 4)
void k_all(const int* __restrict__ sent,
           const float* __restrict__ W,
           const float* __restrict__ trans,
           const float* __restrict__ outw,
           float* __restrict__ out) {
    __shared__ alignas(16) float Elds[ROWS][EPAD];   // 14144 B
    __shared__ alignas(16) float prl[TPB][PRPAD];    // 12288 B
    __shared__ float Tl[100];
    __shared__ float Ttl[100];
    __shared__ float Ol[NST][NLBL];                  // 2000 B

    const int tid = threadIdx.x;
    const int b   = (int)blockIdx.x >> 2;
    const int tb  = ((int)blockIdx.x & 3) * TPB;

    // ---- parallel, max-free param prep (params bounded in [-0.5,0.5]) ----
    if (tid < 250) {
        float* of = &Ol[0][0];
        const int i = 2 * tid;
        of[i]     = __expf(outw[i]);
        of[i + 1] = __expf(outw[i + 1]);
    }
    if (tid < NST) {
        float e[10]; float s = 0.f;
        #pragma unroll
        for (int j = 0; j < 10; ++j) { e[j] = __expf(trans[tid*10 + j]); s += e[j]; }
        float inv = 1.f / s;
        #pragma unroll
        for (int j = 0; j < 10; ++j) { Tl[tid*10 + j] = e[j]*inv; Ttl[j*10 + tid] = e[j]*inv; }
    }

    // ---- emission staging: gather W[tok], softmax (max-free), -> LDS ----
    const int* sb = sent + b*TLEN;
    for (int r = tid; r < ROWS; r += 256) {
        int p  = tb - HALO + r;
        int pc = min(max(p, 0), TLEN-1);
        int tok = sb[pc];
        const float2* w2 = reinterpret_cast<const float2*>(W + (size_t)tok*NST);
        float2 q0=w2[0], q1=w2[1], q2=w2[2], q3=w2[3], q4=w2[4];
        float e[10] = {q0.x,q0.y,q1.x,q1.y,q2.x,q2.y,q3.x,q3.y,q4.x,q4.y};
        float s = 0.f;
        #pragma unroll
        for (int j=0;j<10;++j) { e[j] = __expf(e[j]); s += e[j]; }
        float inv = 1.f/s;
        #pragma unroll
        for (int j=0;j<10;++j) Elds[r][j] = e[j]*inv;
    }
    __syncthreads();   // barrier 1: Elds + exp(Ol) + T tables visible

    // ---- Ol row normalization (10 threads; consumed only after barrier 2) ----
    if (tid < NST) {
        float s = 0.f;
        #pragma unroll 10
        for (int l = 0; l < NLBL; ++l) s += Ol[tid][l];
        float inv = 1.f / s;
        #pragma unroll 10
        for (int l = 0; l < NLBL; ++l) Ol[tid][l] *= inv;
    }

    // ---- pair decomposition: lanes (2k,2k+1) share one 2-step chunk ----
    const int q   = tid & 1;          // 0: states 0..4, 1: states 5..9
    const int pr_ = tid >> 1;         // pair index 0..127
    const int j0  = 5*q;
    const int j1  = 5 - j0;           // partner's state base
    const int t0  = tb + 2*pr_;       // chunk = {t0, t0+1}
    const int lr0 = 2*pr_;            // LDS row of position t0-HALO
    const int lre = lr0 + 2*HALO + 1; // LDS row of position t0+HALO+1

    float as0[5], as1[5];
    {
        // ---- forward: 9 steps from t0-HALO; keep alpha(t0), alpha(t0+1) ----
        float Ta[5][5], Tb[5][5];
        #pragma unroll
        for (int r=0;r<5;++r)
            #pragma unroll
            for (int k=0;k<5;++k) {
                Ta[r][k] = Tl[(j0+r)*10 + j0 + k];
                Tb[r][k] = Tl[(j0+r)*10 + j1 + k];
            }

        float m_[5];
        #pragma unroll
        for (int k=0;k<5;++k) m_[k] = Elds[lr0][j0+k] * SC;

        #pragma unroll
        for (int i=1;i<=HALO+1;++i) {
            const int p = t0 - HALO + i;
            float pp[5];
            #pragma unroll
            for (int k=0;k<5;++k) pp[k] = dppswap(m_[k]);
            float an[5];
            #pragma unroll
            for (int r=0;r<5;++r) {
                float accA = 0.f, accB = 0.f;
                #pragma unroll
                for (int k=0;k<5;++k) accA = fmaf(Ta[r][k], m_[k], accA);
                #pragma unroll
                for (int k=0;k<5;++k) accB = fmaf(Tb[r][k], pp[k], accB);
                an[r] = (accA + accB) * Elds[lr0+i][j0+r];
            }
            const bool upd = (p >= 1);
            #pragma unroll
            for (int r=0;r<5;++r) m_[r] = upd ? an[r] : m_[r];
            if (i == HALO) {
                #pragma unroll
                for (int r=0;r<5;++r) as0[r] = m_[r];
            }
        }
        #pragma unroll
        for (int r=0;r<5;++r) as1[r] = m_[r];
    }

    {
        // ---- backward: 9 steps from t0+HALO+1 down to t0; posterior -> prl ----
        float Ta[5][5], Tb[5][5];
        #pragma unroll
        for (int r=0;r<5;++r)
            #pragma unroll
            for (int k=0;k<5;++k) {
                Ta[r][k] = Ttl[(j0+r)*10 + j0 + k];
                Tb[r][k] = Ttl[(j0+r)*10 + j1 + k];
            }

        const int pe = t0 + HALO + 1;
        float g_[5];
        #pragma unroll
        for (int k=0;k<5;++k) g_[k] = Elds[lre][j0+k] * SC;

        #pragma unroll
        for (int i=1;i<=HALO+1;++i) {
            const int p = pe - i;
            float pp[5];
            #pragma unroll
            for (int k=0;k<5;++k) pp[k] = dppswap(g_[k]);
            float u[5];
            #pragma unroll
            for (int r=0;r<5;++r) {
                float accA = 0.f, accB = 0.f;
                #pragma unroll
                for (int k=0;k<5;++k) accA = fmaf(Ta[r][k], g_[k], accA);
                #pragma unroll
                for (int k=0;k<5;++k) accB = fmaf(Tb[r][k], pp[k], accB);
                u[r] = accA + accB;
            }
            const bool last = (p == TLEN-1);
            #pragma unroll
            for (int r=0;r<5;++r) u[r] = last ? SC : u[r];
            if (i == HALO) {          // p == t0+1
                float pv[5]; float sum = 0.f;
                #pragma unroll
                for (int r=0;r<5;++r) { pv[r] = as1[r]*u[r]; sum += pv[r]; }
                float full = sum + dppswap(sum);
                #pragma unroll
                for (int r=0;r<5;++r) prl[2*pr_+1][j0+r] = pv[r];
                prl[2*pr_+1][10] = __log2f(full);
            }
            if (i == HALO+1) {        // p == t0
                float pv[5]; float sum = 0.f;
                #pragma unroll
                for (int r=0;r<5;++r) { pv[r] = as0[r]*u[r]; sum += pv[r]; }
                float full = sum + dppswap(sum);
                #pragma unroll
                for (int r=0;r<5;++r) prl[2*pr_][j0+r] = pv[r];
                prl[2*pr_][10] = __log2f(full);
            }
            const bool keep = (p > TLEN-1);
            #pragma unroll
            for (int r=0;r<5;++r) {
                float gn = Elds[lre - i][j0+r] * u[r];
                g_[r] = keep ? g_[r] : gn;
            }
        }
    }
    __syncthreads();   // barrier 2: prl visible; Ol normalized

    // ---- combine: 8 lanes per row x 7 labels; direct global stores (R9/R13: no
    //      write amplification from scattered 28B stores), no LDS staging ----
    const int wid  = tid >> 6;
    const int lane = tid & 63;
    const int lg = lane & 7;              // label group
    const int rv = lane >> 3;             // 0..7
    const int lb = lg * 7;                // labels lb..lb+6 (masked at 50)

    float vO[10][7];
    #pragma unroll
    for (int s=0;s<10;++s)
        #pragma unroll
        for (int k=0;k<7;++k) vO[s][k] = (lb + k < NLBL) ? Ol[s][lb+k] : 0.f;

    float* obW = out + ((size_t)b*TLEN + tb + wid*64)*NLBL;
    #pragma unroll 2
    for (int pass = 0; pass < 8; ++pass) {
        const int rloc = rv + 8*pass;         // row within wave's 64-row span
        const int t = wid*64 + rloc;          // block row
        const float4* pr4 = reinterpret_cast<const float4*>(&prl[t][0]);
        const float4 pA = pr4[0];
        const float4 pB = pr4[1];
        const float4 pC = pr4[2];             // [8],[9],[10]=ls,[11] unused
        float pv[10] = {pA.x,pA.y,pA.z,pA.w,pB.x,pB.y,pB.z,pB.w,pC.x,pC.y};
        const float ls = pC.z;
        float* orow = obW + rloc*NLBL + lb;
        #pragma unroll
        for (int k=0;k<7;++k) {
            float d = 0.f;
            #pragma unroll
            for (int s=0;s<10;++s) d = fmaf(pv[s], vO[s][k], d);
            float v = (__log2f(d) - ls) * LN2F;
            if (lb + k < NLBL) orow[k] = v;
        }
    }
}

extern "C" void kernel_launch(void* const* d_in, const int* in_sizes, int n_in,
                              void* d_out, int out_size, void* d_ws, size_t ws_size,
                              hipStream_t stream) {
    const int*   sent  = (const int*)d_in[0];
    const float* W     = (const float*)d_in[1];
    const float* trans = (const float*)d_in[2];
    const float* outw  = (const float*)d_in[3];
    float* out = (float*)d_out;

    hipLaunchKernelGGL(k_all, dim3(BATCH * (TLEN / TPB)), dim3(256), 0, stream,
                       sent, W, trans, outw, out);
}

// Round 19
// 31.119 us; speedup vs baseline: 1.5877x; 1.5527x over previous
//
#include <hip/hip_runtime.h>

#define NST 10
#define NLBL 50
#define BATCH 256
#define TLEN 1024
#define TPB 256
#define HALO 8
#define ROWS (TPB + 2*HALO)   // 272
#define EPAD 13
#define PRPAD 12
#define SC 1.0e15f
#define LN2F 0.69314718055994531f

static __device__ __forceinline__ float dppswap(float x) {
    // quad_perm [1,0,3,2]: lane 2k <-> 2k+1. Pure VALU, no LDS.
    return __int_as_float(__builtin_amdgcn_mov_dpp(__float_as_int(x), 0xB1, 0xF, 0xF, true));
}

__global__ __launch_bounds__(256, 4)
void k_all(const int* __restrict__ sent,
           const float* __restrict__ W,
           const float* __restrict__ trans,
           const float* __restrict__ outw,
           float* __restrict__ out) {
    // Elds doubles as per-wave combine staging (4 waves x 800 floats = 3200 <= 272*13).
    __shared__ alignas(16) float Elds[ROWS][EPAD];   // 14144 B
    __shared__ alignas(16) float prl[TPB][PRPAD];    // 12288 B
    __shared__ float Tl[100];
    __shared__ float Ttl[100];
    __shared__ float Ol[NST][NLBL];                  // 2000 B

    const int tid = threadIdx.x;
    const int b   = (int)blockIdx.x >> 2;
    const int tb  = ((int)blockIdx.x & 3) * TPB;

    // ---- parallel, max-free param prep (params bounded in [-0.5,0.5]) ----
    if (tid < 250) {
        float* of = &Ol[0][0];
        const int i = 2 * tid;
        of[i]     = __expf(outw[i]);
        of[i + 1] = __expf(outw[i + 1]);
    }
    if (tid < NST) {
        float e[10]; float s = 0.f;
        #pragma unroll
        for (int j = 0; j < 10; ++j) { e[j] = __expf(trans[tid*10 + j]); s += e[j]; }
        float inv = 1.f / s;
        #pragma unroll
        for (int j = 0; j < 10; ++j) { Tl[tid*10 + j] = e[j]*inv; Ttl[j*10 + tid] = e[j]*inv; }
    }

    // ---- emission staging: gather W[tok], softmax (max-free), -> LDS ----
    const int* sb = sent + b*TLEN;
    for (int r = tid; r < ROWS; r += 256) {
        int p  = tb - HALO + r;
        int pc = min(max(p, 0), TLEN-1);
        int tok = sb[pc];
        const float2* w2 = reinterpret_cast<const float2*>(W + (size_t)tok*NST);
        float2 q0=w2[0], q1=w2[1], q2=w2[2], q3=w2[3], q4=w2[4];
        float e[10] = {q0.x,q0.y,q1.x,q1.y,q2.x,q2.y,q3.x,q3.y,q4.x,q4.y};
        float s = 0.f;
        #pragma unroll
        for (int j=0;j<10;++j) { e[j] = __expf(e[j]); s += e[j]; }
        float inv = 1.f/s;
        #pragma unroll
        for (int j=0;j<10;++j) Elds[r][j] = e[j]*inv;
    }
    __syncthreads();   // barrier 1: Elds + exp(Ol) visible

    // ---- Ol row normalization (10 threads; consumed only after barrier 2) ----
    if (tid < NST) {
        float s = 0.f;
        #pragma unroll 10
        for (int l = 0; l < NLBL; ++l) s += Ol[tid][l];
        float inv = 1.f / s;
        #pragma unroll 10
        for (int l = 0; l < NLBL; ++l) Ol[tid][l] *= inv;
    }

    // ---- pair decomposition: lanes (2k,2k+1) share one 2-step chunk ----
    const int q   = tid & 1;          // 0: states 0..4, 1: states 5..9
    const int pr_ = tid >> 1;         // pair index 0..127
    const int j0  = 5*q;
    const int j1  = 5 - j0;           // partner's state base
    const int t0  = tb + 2*pr_;       // chunk = {t0, t0+1}
    const int lr0 = 2*pr_;            // LDS row of position t0-HALO
    const int lre = lr0 + 2*HALO + 1; // LDS row of position t0+HALO+1

    float as0[5], as1[5];
    {
        // ---- forward: 9 steps from t0-HALO; keep alpha(t0), alpha(t0+1) ----
        float Ta[5][5], Tb[5][5];
        #pragma unroll
        for (int r=0;r<5;++r)
            #pragma unroll
            for (int k=0;k<5;++k) {
                Ta[r][k] = Tl[(j0+r)*10 + j0 + k];
                Tb[r][k] = Tl[(j0+r)*10 + j1 + k];
            }

        float m_[5];
        #pragma unroll
        for (int k=0;k<5;++k) m_[k] = Elds[lr0][j0+k] * SC;

        #pragma unroll
        for (int i=1;i<=HALO+1;++i) {
            const int p = t0 - HALO + i;
            float pp[5];
            #pragma unroll
            for (int k=0;k<5;++k) pp[k] = dppswap(m_[k]);
            float an[5];
            #pragma unroll
            for (int r=0;r<5;++r) {
                float accA = 0.f, accB = 0.f;
                #pragma unroll
                for (int k=0;k<5;++k) accA = fmaf(Ta[r][k], m_[k], accA);
                #pragma unroll
                for (int k=0;k<5;++k) accB = fmaf(Tb[r][k], pp[k], accB);
                an[r] = (accA + accB) * Elds[lr0+i][j0+r];
            }
            const bool upd = (p >= 1);
            #pragma unroll
            for (int r=0;r<5;++r) m_[r] = upd ? an[r] : m_[r];
            if (i == HALO) {
                #pragma unroll
                for (int r=0;r<5;++r) as0[r] = m_[r];
            }
        }
        #pragma unroll
        for (int r=0;r<5;++r) as1[r] = m_[r];
    }

    {
        // ---- backward: 9 steps from t0+HALO+1 down to t0; posterior -> prl ----
        float Ta[5][5], Tb[5][5];
        #pragma unroll
        for (int r=0;r<5;++r)
            #pragma unroll
            for (int k=0;k<5;++k) {
                Ta[r][k] = Ttl[(j0+r)*10 + j0 + k];
                Tb[r][k] = Ttl[(j0+r)*10 + j1 + k];
            }

        const int pe = t0 + HALO + 1;
        float g_[5];
        #pragma unroll
        for (int k=0;k<5;++k) g_[k] = Elds[lre][j0+k] * SC;

        #pragma unroll
        for (int i=1;i<=HALO+1;++i) {
            const int p = pe - i;
            float pp[5];
            #pragma unroll
            for (int k=0;k<5;++k) pp[k] = dppswap(g_[k]);
            float u[5];
            #pragma unroll
            for (int r=0;r<5;++r) {
                float accA = 0.f, accB = 0.f;
                #pragma unroll
                for (int k=0;k<5;++k) accA = fmaf(Ta[r][k], g_[k], accA);
                #pragma unroll
                for (int k=0;k<5;++k) accB = fmaf(Tb[r][k], pp[k], accB);
                u[r] = accA + accB;
            }
            const bool last = (p == TLEN-1);
            #pragma unroll
            for (int r=0;r<5;++r) u[r] = last ? SC : u[r];
            if (i == HALO) {          // p == t0+1
                float pv[5]; float sum = 0.f;
                #pragma unroll
                for (int r=0;r<5;++r) { pv[r] = as1[r]*u[r]; sum += pv[r]; }
                float full = sum + dppswap(sum);
                #pragma unroll
                for (int r=0;r<5;++r) prl[2*pr_+1][j0+r] = pv[r];
                prl[2*pr_+1][10] = __log2f(full);
            }
            if (i == HALO+1) {        // p == t0
                float pv[5]; float sum = 0.f;
                #pragma unroll
                for (int r=0;r<5;++r) { pv[r] = as0[r]*u[r]; sum += pv[r]; }
                float full = sum + dppswap(sum);
                #pragma unroll
                for (int r=0;r<5;++r) prl[2*pr_][j0+r] = pv[r];
                prl[2*pr_][10] = __log2f(full);
            }
            const bool keep = (p > TLEN-1);
            #pragma unroll
            for (int r=0;r<5;++r) {
                float gn = Elds[lre - i][j0+r] * u[r];
                g_[r] = keep ? g_[r] : gn;
            }
        }
    }
    __syncthreads();   // barrier 2: all Elds reads done (stage reuse safe); Ol normalized

    // ---- combine: wave-local, zero barriers; 16 lanes/row x 4 labels (vO = 40 regs) ----
    const int wid  = tid >> 6;
    const int lane = tid & 63;
    const int lg = lane & 15;             // label group 0..15
    const int rv = lane >> 4;             // 0..3
    const int lb = lg * 4;                // labels lb..lb+3 (masked at 50)
    float* stageW = &Elds[0][0] + wid * 800;

    float vO[10][4];
    #pragma unroll
    for (int s=0;s<10;++s)
        #pragma unroll
        for (int k=0;k<4;++k) vO[s][k] = (lb + k < NLBL) ? Ol[s][lb+k] : 0.f;

    float* obW = out + ((size_t)b*TLEN + tb + wid*64)*NLBL;
    #pragma unroll 1
    for (int til = 0; til < 4; ++til) {
        #pragma unroll
        for (int jr = 0; jr < 4; ++jr) {
            const int rloc = rv + 4*jr;           // row within tile [0,16)
            const int t = wid*64 + til*16 + rloc; // block row
            const float4* pr4 = reinterpret_cast<const float4*>(&prl[t][0]);
            const float4 pA = pr4[0];
            const float4 pB = pr4[1];
            const float4 pC = pr4[2];             // [8],[9],[10]=ls,[11] unused
            float pv[10] = {pA.x,pA.y,pA.z,pA.w,pB.x,pB.y,pB.z,pB.w,pC.x,pC.y};
            const float ls = pC.z;
            #pragma unroll
            for (int k=0;k<4;++k) {
                float d = 0.f;
                #pragma unroll
                for (int s=0;s<10;++s) d = fmaf(pv[s], vO[s][k], d);
                float v = (__log2f(d) - ls) * LN2F;
                if (lb + k < NLBL) stageW[rloc*NLBL + lb + k] = v;
            }
        }
        // copy tile: 16 rows x 50 = 800 dwords = 200 float4 per wave
        const float4* s4 = reinterpret_cast<const float4*>(stageW);
        float4* d4 = reinterpret_cast<float4*>(obW + til*16*NLBL);
        d4[lane]        = s4[lane];
        d4[lane + 64]   = s4[lane + 64];
        d4[lane + 128]  = s4[lane + 128];
        if (lane < 8) d4[lane + 192] = s4[lane + 192];
    }
}

extern "C" void kernel_launch(void* const* d_in, const int* in_sizes, int n_in,
                              void* d_out, int out_size, void* d_ws, size_t ws_size,
                              hipStream_t stream) {
    const int*   sent  = (const int*)d_in[0];
    const float* W     = (const float*)d_in[1];
    const float* trans = (const float*)d_in[2];
    const float* outw  = (const float*)d_in[3];
    float* out = (float*)d_out;

    hipLaunchKernelGGL(k_all, dim3(BATCH * (TLEN / TPB)), dim3(256), 0, stream,
                       sent, W, trans, outw, out);
}